// Round 11
// baseline (336.704 us; speedup 1.0000x reference)
//
#include <hip/hip_runtime.h>
#include <math.h>

#define IN_C 128
#define HID 32
#define HEADS 4
#define OUT_C 128
#define NEG_SLOPE 0.2f

typedef unsigned int uint_t;
typedef unsigned short ushort_t;
typedef _Float16 half8 __attribute__((ext_vector_type(8)));
typedef float floatx4 __attribute__((ext_vector_type(4)));
typedef float v2f __attribute__((ext_vector_type(2)));

// f32 -> bf16 round-to-nearest-even
__device__ __forceinline__ ushort_t f2bf(float f) {
    uint_t u = __float_as_uint(f);
    u = (u + 0x7fffu + ((u >> 16) & 1u)) >> 16;
    return (ushort_t)u;
}
// one uint = 2 bf16 channels -> v2f (low ushort = lower channel)
__device__ __forceinline__ v2f bf2v2(uint_t u) {
    v2f r;
    r[0] = __uint_as_float(u << 16);
    r[1] = __uint_as_float(u & 0xffff0000u);
    return r;
}

// ---------- MFMA dual transform: outl(bf16) = x@Wl, outr(f32) = x@Wr ----------
#define XPAD 136
__global__ __launch_bounds__(256) void transform_mfma(
        const float* __restrict__ x,
        const float* __restrict__ Wl,
        const float* __restrict__ Wr,
        ushort_t* __restrict__ outl,
        float* __restrict__ outr, int n) {
    __shared__ _Float16 xs[16 * XPAD + 8];
    const int tid = threadIdx.x;
    const int wv = tid >> 6;
    const int l  = tid & 63;
    const int lm = l & 15;
    const int quad = l >> 4;
    const int kb = quad * 8;

    const float* Wsel = (wv < 2) ? Wl : Wr;
    const int nbase = (wv & 1) * 64;
    half8 bw[4][4];
#pragma unroll
    for (int t = 0; t < 4; ++t) {
        const int ncol = nbase + t * 16 + lm;
#pragma unroll
        for (int K = 0; K < 4; ++K) {
            const int k0 = K * 32 + kb;
            half8 h;
#pragma unroll
            for (int j = 0; j < 8; ++j)
                h[j] = (_Float16)Wsel[(size_t)(k0 + j) * IN_C + ncol];
            bw[t][K] = h;
        }
    }

    const int nStrips = (n + 15) >> 4;
    for (int s = blockIdx.x; s < nStrips; s += gridDim.x) {
        const int row0 = s * 16;
        __syncthreads();
        {
            const int srow = tid >> 4;
            const int sc = (tid & 15) * 8;
            const int grow = row0 + srow;
            float4 v0 = make_float4(0.f, 0.f, 0.f, 0.f);
            float4 v1 = make_float4(0.f, 0.f, 0.f, 0.f);
            if (grow < n) {
                v0 = *(const float4*)&x[(size_t)grow * IN_C + sc];
                v1 = *(const float4*)&x[(size_t)grow * IN_C + sc + 4];
            }
            half8 h;
            h[0] = (_Float16)v0.x; h[1] = (_Float16)v0.y;
            h[2] = (_Float16)v0.z; h[3] = (_Float16)v0.w;
            h[4] = (_Float16)v1.x; h[5] = (_Float16)v1.y;
            h[6] = (_Float16)v1.z; h[7] = (_Float16)v1.w;
            *(half8*)&xs[srow * XPAD + sc] = h;
        }
        __syncthreads();
        half8 af[4];
#pragma unroll
        for (int K = 0; K < 4; ++K)
            af[K] = *(half8*)&xs[lm * XPAD + K * 32 + kb];
        floatx4 acc[4];
#pragma unroll
        for (int t = 0; t < 4; ++t) acc[t] = (floatx4){0.f, 0.f, 0.f, 0.f};
#pragma unroll
        for (int t = 0; t < 4; ++t)
#pragma unroll
            for (int K = 0; K < 4; ++K)
                acc[t] = __builtin_amdgcn_mfma_f32_16x16x32_f16(af[K], bw[t][K], acc[t], 0, 0, 0);
#pragma unroll
        for (int t = 0; t < 4; ++t) {
            const int col = nbase + t * 16 + lm;
#pragma unroll
            for (int r = 0; r < 4; ++r) {
                const int row = row0 + quad * 4 + r;
                if (row < n) {
                    if (wv < 2) outl[(size_t)row * IN_C + col] = f2bf(acc[t][r]);
                    else        outr[(size_t)row * IN_C + col] = acc[t][r];
                }
            }
        }
    }
}

// ---------- CSR build ----------
__global__ void hist_kernel(const int* __restrict__ dst, int* __restrict__ cnt, int E) {
    int e = blockIdx.x * blockDim.x + threadIdx.x;
    if (e < E) atomicAdd(&cnt[dst[e]], 1);
}

__global__ void scan_block_sums(const int* __restrict__ cnt, int* __restrict__ part, int n) {
    __shared__ int sdata[256];
    int t = threadIdx.x;
    int i = blockIdx.x * 256 + t;
    sdata[t] = (i < n) ? cnt[i] : 0;
    __syncthreads();
    for (int o = 128; o >= 1; o >>= 1) {
        if (t < o) sdata[t] += sdata[t + o];
        __syncthreads();
    }
    if (t == 0) part[blockIdx.x] = sdata[0];
}

__global__ void scan_part_excl(int* __restrict__ part, int nb) {  // single block
    __shared__ int buf[1024];
    int t = threadIdx.x;
    int v = (t < nb) ? part[t] : 0;
    buf[t] = v;
    __syncthreads();
    for (int o = 1; o < 1024; o <<= 1) {
        int a = (t >= o) ? buf[t - o] : 0;
        __syncthreads();
        buf[t] += a;
        __syncthreads();
    }
    if (t < nb) part[t] = buf[t] - v;   // exclusive
}

// also seeds cursor[] = rowptr[] so scatter's atomic gives the absolute slot
__global__ void scan_final(const int* __restrict__ cnt, const int* __restrict__ part,
                           int* __restrict__ rowptr, int* __restrict__ cursor, int n) {
    __shared__ int buf[256];
    int t = threadIdx.x;
    int i = blockIdx.x * 256 + t;
    int v = (i < n) ? cnt[i] : 0;
    buf[t] = v;
    __syncthreads();
    for (int o = 1; o < 256; o <<= 1) {
        int a = (t >= o) ? buf[t - o] : 0;
        __syncthreads();
        buf[t] += a;
        __syncthreads();
    }
    int excl = part[blockIdx.x] + buf[t] - v;
    if (i < n) { rowptr[i] = excl; cursor[i] = excl; }
    if (i == n - 1) rowptr[n] = excl + v;
}

__global__ void scatter_csr(const int* __restrict__ src,
                            const int* __restrict__ dst,
                            int* __restrict__ cursor,
                            ushort_t* __restrict__ gsrc, int E) {
    int e = blockIdx.x * blockDim.x + threadIdx.x;
    if (e >= E) return;
    int pos = atomicAdd(&cursor[dst[e]], 1);
    gsrc[pos] = (ushort_t)src[e];
}

// ---------- fused kernels: 16-lane group per edge, 4 edges/wave ----------
// Branch-free, batched loads, packed (v2f) math throughout.

// layer 1: 4 heads x 32ch; head of lane = q>>2; reduce within 4 lanes.
__global__ __launch_bounds__(256) void node_fused1(
        const ushort_t* __restrict__ xlb,
        const float* __restrict__ xr,
        const float* __restrict__ att,
        const int* __restrict__ rowptr,
        const ushort_t* __restrict__ gsrc,
        const float* __restrict__ b,
        float* __restrict__ hout, int N) {
    const int wv = threadIdx.x >> 6;
    const int l  = threadIdx.x & 63;
    const int g  = l >> 4, q = l & 15;
    const int d  = blockIdx.x * 4 + wv;
    if (d >= N) return;
    const int beg = rowptr[d], end = rowptr[d + 1];
    const int cb = q * 8;
    v2f xr2[4], a2[4];
#pragma unroll
    for (int j = 0; j < 4; ++j) {
        xr2[j] = *(const v2f*)&xr[(size_t)d * IN_C + cb + 2 * j];
        a2[j]  = *(const v2f*)&att[cb + 2 * j];
    }
    float m = -1e30f, ls = 0.f;
    v2f acc2[4];
#pragma unroll
    for (int j = 0; j < 4; ++j) acc2[j] = (v2f){0.f, 0.f};
    for (int c0 = beg; c0 < end; c0 += 16) {
        int sA[4];
#pragma unroll
        for (int u = 0; u < 4; ++u) {
            int j = c0 + 4 * u + g;
            sA[u] = (int)gsrc[min(j, end - 1)];
        }
        uint4 w[4];
#pragma unroll
        for (int u = 0; u < 4; ++u)
            w[u] = *(const uint4*)&xlb[(size_t)(sA[u] * IN_C) + cb];
        float f[4];
        v2f vs[4][4];
#pragma unroll
        for (int u = 0; u < 4; ++u) {
            vs[u][0] = bf2v2(w[u].x); vs[u][1] = bf2v2(w[u].y);
            vs[u][2] = bf2v2(w[u].z); vs[u][3] = bf2v2(w[u].w);
            v2f p2 = (v2f){0.f, 0.f};
#pragma unroll
            for (int j = 0; j < 4; ++j) {
                v2f t = vs[u][j] + xr2[j];
                v2f lr = __builtin_elementwise_max(t, t * 0.2f);
                p2 = __builtin_elementwise_fma(lr, a2[j], p2);
            }
            float p = p2[0] + p2[1];
            p += __shfl_xor(p, 1, 64);
            p += __shfl_xor(p, 2, 64);
            f[u] = (c0 + 4 * u + g < end) ? p : -1e30f;
        }
        float bm = fmaxf(fmaxf(f[0], f[1]), fmaxf(f[2], f[3]));
        float nm = fmaxf(m, bm);
        float fc = __expf(m - nm);
        ls *= fc;
        v2f fc2 = (v2f){fc, fc};
#pragma unroll
        for (int j = 0; j < 4; ++j) acc2[j] *= fc2;
#pragma unroll
        for (int u = 0; u < 4; ++u) {
            float wgt = __expf(f[u] - nm);
            ls += wgt;
            v2f wg2 = (v2f){wgt, wgt};
#pragma unroll
            for (int j = 0; j < 4; ++j)
                acc2[j] = __builtin_elementwise_fma(wg2, vs[u][j], acc2[j]);
        }
        m = nm;
    }
    // merge 4 groups (xor 16/32 partners share q -> same head)
#pragma unroll
    for (int o = 16; o <= 32; o <<= 1) {
        float mo = __shfl_xor(m, o, 64);
        float lo = __shfl_xor(ls, o, 64);
        v2f ao[4];
#pragma unroll
        for (int j = 0; j < 4; ++j) {
            ao[j][0] = __shfl_xor(acc2[j][0], o, 64);
            ao[j][1] = __shfl_xor(acc2[j][1], o, 64);
        }
        float nm = fmaxf(m, mo);
        float fs = __expf(m - nm), fo = __expf(mo - nm);
        ls = ls * fs + lo * fo;
        v2f fs2 = (v2f){fs, fs}, fo2 = (v2f){fo, fo};
#pragma unroll
        for (int j = 0; j < 4; ++j)
            acc2[j] = __builtin_elementwise_fma(ao[j], fo2, acc2[j] * fs2);
        m = nm;
    }
    if (g == 0) {
        float inv = (ls > 0.f) ? 1.f / ls : 0.f;
        v2f inv2 = (v2f){inv, inv};
        float4 o1, o2;
        float ov[8];
#pragma unroll
        for (int j = 0; j < 4; ++j) {
            v2f b2 = *(const v2f*)&b[cb + 2 * j];
            v2f o = __builtin_elementwise_fma(acc2[j], inv2, b2);
            ov[2 * j]     = (o[0] > 0.f) ? o[0] : expm1f(o[0]);
            ov[2 * j + 1] = (o[1] > 0.f) ? o[1] : expm1f(o[1]);
        }
        o1 = make_float4(ov[0], ov[1], ov[2], ov[3]);
        o2 = make_float4(ov[4], ov[5], ov[6], ov[7]);
        *(float4*)&hout[(size_t)d * IN_C + cb]     = o1;
        *(float4*)&hout[(size_t)d * IN_C + cb + 4] = o2;
    }
}

// layer 2: single head x 128ch; reduce within all 16 lanes of the group.
__global__ __launch_bounds__(256) void node_fused2(
        const ushort_t* __restrict__ xlb,
        const float* __restrict__ xr,
        const float* __restrict__ att,
        const int* __restrict__ rowptr,
        const ushort_t* __restrict__ gsrc,
        const float* __restrict__ b,
        float* __restrict__ out, int N) {
    const int wv = threadIdx.x >> 6;
    const int l  = threadIdx.x & 63;
    const int g  = l >> 4, q = l & 15;
    const int d  = blockIdx.x * 4 + wv;
    if (d >= N) return;
    const int beg = rowptr[d], end = rowptr[d + 1];
    const int cb = q * 8;
    v2f xr2[4], a2[4];
#pragma unroll
    for (int j = 0; j < 4; ++j) {
        xr2[j] = *(const v2f*)&xr[(size_t)d * OUT_C + cb + 2 * j];
        a2[j]  = *(const v2f*)&att[cb + 2 * j];
    }
    float m = -1e30f, ls = 0.f;
    v2f acc2[4];
#pragma unroll
    for (int j = 0; j < 4; ++j) acc2[j] = (v2f){0.f, 0.f};
    for (int c0 = beg; c0 < end; c0 += 16) {
        int sA[4];
#pragma unroll
        for (int u = 0; u < 4; ++u) {
            int j = c0 + 4 * u + g;
            sA[u] = (int)gsrc[min(j, end - 1)];
        }
        uint4 w[4];
#pragma unroll
        for (int u = 0; u < 4; ++u)
            w[u] = *(const uint4*)&xlb[(size_t)(sA[u] * OUT_C) + cb];
        float f[4];
        v2f vs[4][4];
#pragma unroll
        for (int u = 0; u < 4; ++u) {
            vs[u][0] = bf2v2(w[u].x); vs[u][1] = bf2v2(w[u].y);
            vs[u][2] = bf2v2(w[u].z); vs[u][3] = bf2v2(w[u].w);
            v2f p2 = (v2f){0.f, 0.f};
#pragma unroll
            for (int j = 0; j < 4; ++j) {
                v2f t = vs[u][j] + xr2[j];
                v2f lr = __builtin_elementwise_max(t, t * 0.2f);
                p2 = __builtin_elementwise_fma(lr, a2[j], p2);
            }
            float p = p2[0] + p2[1];
            p += __shfl_xor(p, 1, 64);
            p += __shfl_xor(p, 2, 64);
            p += __shfl_xor(p, 4, 64);
            p += __shfl_xor(p, 8, 64);
            f[u] = (c0 + 4 * u + g < end) ? p : -1e30f;
        }
        float bm = fmaxf(fmaxf(f[0], f[1]), fmaxf(f[2], f[3]));
        float nm = fmaxf(m, bm);
        float fc = __expf(m - nm);
        ls *= fc;
        v2f fc2 = (v2f){fc, fc};
#pragma unroll
        for (int j = 0; j < 4; ++j) acc2[j] *= fc2;
#pragma unroll
        for (int u = 0; u < 4; ++u) {
            float wgt = __expf(f[u] - nm);
            ls += wgt;
            v2f wg2 = (v2f){wgt, wgt};
#pragma unroll
            for (int j = 0; j < 4; ++j)
                acc2[j] = __builtin_elementwise_fma(wg2, vs[u][j], acc2[j]);
        }
        m = nm;
    }
#pragma unroll
    for (int o = 16; o <= 32; o <<= 1) {
        float mo = __shfl_xor(m, o, 64);
        float lo = __shfl_xor(ls, o, 64);
        v2f ao[4];
#pragma unroll
        for (int j = 0; j < 4; ++j) {
            ao[j][0] = __shfl_xor(acc2[j][0], o, 64);
            ao[j][1] = __shfl_xor(acc2[j][1], o, 64);
        }
        float nm = fmaxf(m, mo);
        float fs = __expf(m - nm), fo = __expf(mo - nm);
        ls = ls * fs + lo * fo;
        v2f fs2 = (v2f){fs, fs}, fo2 = (v2f){fo, fo};
#pragma unroll
        for (int j = 0; j < 4; ++j)
            acc2[j] = __builtin_elementwise_fma(ao[j], fo2, acc2[j] * fs2);
        m = nm;
    }
    if (g == 0) {
        float inv = (ls > 0.f) ? 1.f / ls : 0.f;
        v2f inv2 = (v2f){inv, inv};
        float ov[8];
#pragma unroll
        for (int j = 0; j < 4; ++j) {
            v2f b2 = *(const v2f*)&b[cb + 2 * j];
            v2f o = __builtin_elementwise_fma(acc2[j], inv2, b2);
            ov[2 * j] = o[0]; ov[2 * j + 1] = o[1];
        }
        *(float4*)&out[(size_t)d * OUT_C + cb]     = make_float4(ov[0], ov[1], ov[2], ov[3]);
        *(float4*)&out[(size_t)d * OUT_C + cb + 4] = make_float4(ov[4], ov[5], ov[6], ov[7]);
    }
}

extern "C" void kernel_launch(void* const* d_in, const int* in_sizes, int n_in,
                              void* d_out, int out_size, void* d_ws, size_t ws_size,
                              hipStream_t stream) {
    const float* x    = (const float*)d_in[0];
    const int*   ei   = (const int*)d_in[1];
    const float* W1l  = (const float*)d_in[2];
    const float* W1r  = (const float*)d_in[3];
    const float* att1 = (const float*)d_in[4];
    const float* b1   = (const float*)d_in[5];
    const float* W2l  = (const float*)d_in[6];
    const float* W2r  = (const float*)d_in[7];
    const float* att2 = (const float*)d_in[8];
    const float* b2   = (const float*)d_in[9];

    const int N = in_sizes[0] / IN_C;
    const int E = in_sizes[1] / 2;
    const int* src = ei;
    const int* dst = ei + E;

    // workspace layout
    float* ws = (float*)d_ws;
    size_t o = 0;
    ushort_t* xlb = (ushort_t*)(ws + o); o += (size_t)N * IN_C / 2;  // bf16 x@Wl / h@W2l
    float* xr   = ws + o; o += (size_t)N * IN_C;   // x@Wr (layer1) / h@W2r (layer2)
    float* hbuf = ws + o; o += (size_t)N * IN_C;   // layer1 output h (post ELU, f32)
    int* iws    = (int*)(ws + o);
    int* rowptr = iws;                    // N+1
    int* cnt    = iws + (N + 1);          // N
    int* cursor = iws + (N + 1) + N;      // N   (seeded by scan_final)
    int* part   = iws + (N + 1) + 2 * N;  // <=1024 block partials
    ushort_t* gsrc = (ushort_t*)(iws + (N + 1) + 2 * N + 1024);  // E (CSR src ids)

    hipMemsetAsync(cnt, 0, (size_t)N * 4, stream);

    const int B = 256;
    const int nb = (N + 255) / 256;   // scan blocks (196 <= 1024)
    // ---- CSR by dst (shared by both layers) ----
    hist_kernel<<<(E + B - 1) / B, B, 0, stream>>>(dst, cnt, E);
    scan_block_sums<<<nb, 256, 0, stream>>>(cnt, part, N);
    scan_part_excl<<<1, 1024, 0, stream>>>(part, nb);
    scan_final<<<nb, 256, 0, stream>>>(cnt, part, rowptr, cursor, N);
    scatter_csr<<<(E + B - 1) / B, B, 0, stream>>>(src, dst, cursor, gsrc, E);

    // ---- layer 1 ----
    transform_mfma<<<512, 256, 0, stream>>>(x, W1l, W1r, xlb, xr, N);
    node_fused1<<<(N + 3) / 4, 256, 0, stream>>>(xlb, xr, att1, rowptr, gsrc, b1, hbuf, N);

    // ---- layer 2 ----
    transform_mfma<<<512, 256, 0, stream>>>(hbuf, W2l, W2r, xlb, xr, N);
    node_fused2<<<(N + 3) / 4, 256, 0, stream>>>(xlb, xr, att2, rowptr, gsrc, b2, (float*)d_out, N);
}

// Round 12
// 314.710 us; speedup vs baseline: 1.0699x; 1.0699x over previous
//
#include <hip/hip_runtime.h>
#include <math.h>

#define IN_C 128
#define HID 32
#define HEADS 4
#define OUT_C 128
#define NEG_SLOPE 0.2f

typedef unsigned int uint_t;
typedef unsigned short ushort_t;
typedef _Float16 half8 __attribute__((ext_vector_type(8)));
typedef float floatx4 __attribute__((ext_vector_type(4)));

// f32 -> bf16 round-to-nearest-even
__device__ __forceinline__ ushort_t f2bf(float f) {
    uint_t u = __float_as_uint(f);
    u = (u + 0x7fffu + ((u >> 16) & 1u)) >> 16;
    return (ushort_t)u;
}
// one uint = 2 bf16 channels -> 2 floats (low ushort = lower channel)
__device__ __forceinline__ float2 bf2f2(uint_t u) {
    float2 r;
    r.x = __uint_as_float(u << 16);
    r.y = __uint_as_float(u & 0xffff0000u);
    return r;
}

// ---------- MFMA dual transform: outl(bf16) = x@Wl, outr(f32) = x@Wr ----------
#define XPAD 136
__global__ __launch_bounds__(256) void transform_mfma(
        const float* __restrict__ x,
        const float* __restrict__ Wl,
        const float* __restrict__ Wr,
        ushort_t* __restrict__ outl,
        float* __restrict__ outr, int n) {
    __shared__ _Float16 xs[16 * XPAD + 8];
    const int tid = threadIdx.x;
    const int wv = tid >> 6;
    const int l  = tid & 63;
    const int lm = l & 15;
    const int quad = l >> 4;
    const int kb = quad * 8;

    const float* Wsel = (wv < 2) ? Wl : Wr;
    const int nbase = (wv & 1) * 64;
    half8 bw[4][4];
#pragma unroll
    for (int t = 0; t < 4; ++t) {
        const int ncol = nbase + t * 16 + lm;
#pragma unroll
        for (int K = 0; K < 4; ++K) {
            const int k0 = K * 32 + kb;
            half8 h;
#pragma unroll
            for (int j = 0; j < 8; ++j)
                h[j] = (_Float16)Wsel[(size_t)(k0 + j) * IN_C + ncol];
            bw[t][K] = h;
        }
    }

    const int nStrips = (n + 15) >> 4;
    for (int s = blockIdx.x; s < nStrips; s += gridDim.x) {
        const int row0 = s * 16;
        __syncthreads();
        {
            const int srow = tid >> 4;
            const int sc = (tid & 15) * 8;
            const int grow = row0 + srow;
            float4 v0 = make_float4(0.f, 0.f, 0.f, 0.f);
            float4 v1 = make_float4(0.f, 0.f, 0.f, 0.f);
            if (grow < n) {
                v0 = *(const float4*)&x[(size_t)grow * IN_C + sc];
                v1 = *(const float4*)&x[(size_t)grow * IN_C + sc + 4];
            }
            half8 h;
            h[0] = (_Float16)v0.x; h[1] = (_Float16)v0.y;
            h[2] = (_Float16)v0.z; h[3] = (_Float16)v0.w;
            h[4] = (_Float16)v1.x; h[5] = (_Float16)v1.y;
            h[6] = (_Float16)v1.z; h[7] = (_Float16)v1.w;
            *(half8*)&xs[srow * XPAD + sc] = h;
        }
        __syncthreads();
        half8 af[4];
#pragma unroll
        for (int K = 0; K < 4; ++K)
            af[K] = *(half8*)&xs[lm * XPAD + K * 32 + kb];
        floatx4 acc[4];
#pragma unroll
        for (int t = 0; t < 4; ++t) acc[t] = (floatx4){0.f, 0.f, 0.f, 0.f};
#pragma unroll
        for (int t = 0; t < 4; ++t)
#pragma unroll
            for (int K = 0; K < 4; ++K)
                acc[t] = __builtin_amdgcn_mfma_f32_16x16x32_f16(af[K], bw[t][K], acc[t], 0, 0, 0);
#pragma unroll
        for (int t = 0; t < 4; ++t) {
            const int col = nbase + t * 16 + lm;
#pragma unroll
            for (int r = 0; r < 4; ++r) {
                const int row = row0 + quad * 4 + r;
                if (row < n) {
                    if (wv < 2) outl[(size_t)row * IN_C + col] = f2bf(acc[t][r]);
                    else        outr[(size_t)row * IN_C + col] = acc[t][r];
                }
            }
        }
    }
}

// ---------- CSR build ----------
__global__ void hist_kernel(const int* __restrict__ dst, int* __restrict__ cnt, int E) {
    int e = blockIdx.x * blockDim.x + threadIdx.x;
    if (e < E) atomicAdd(&cnt[dst[e]], 1);
}

__global__ void scan_block_sums(const int* __restrict__ cnt, int* __restrict__ part, int n) {
    __shared__ int sdata[256];
    int t = threadIdx.x;
    int i = blockIdx.x * 256 + t;
    sdata[t] = (i < n) ? cnt[i] : 0;
    __syncthreads();
    for (int o = 128; o >= 1; o >>= 1) {
        if (t < o) sdata[t] += sdata[t + o];
        __syncthreads();
    }
    if (t == 0) part[blockIdx.x] = sdata[0];
}

__global__ void scan_part_excl(int* __restrict__ part, int nb) {  // single block
    __shared__ int buf[1024];
    int t = threadIdx.x;
    int v = (t < nb) ? part[t] : 0;
    buf[t] = v;
    __syncthreads();
    for (int o = 1; o < 1024; o <<= 1) {
        int a = (t >= o) ? buf[t - o] : 0;
        __syncthreads();
        buf[t] += a;
        __syncthreads();
    }
    if (t < nb) part[t] = buf[t] - v;   // exclusive
}

// also seeds cursor[] = rowptr[] so scatter's atomic gives the absolute slot
__global__ void scan_final(const int* __restrict__ cnt, const int* __restrict__ part,
                           int* __restrict__ rowptr, int* __restrict__ cursor, int n) {
    __shared__ int buf[256];
    int t = threadIdx.x;
    int i = blockIdx.x * 256 + t;
    int v = (i < n) ? cnt[i] : 0;
    buf[t] = v;
    __syncthreads();
    for (int o = 1; o < 256; o <<= 1) {
        int a = (t >= o) ? buf[t - o] : 0;
        __syncthreads();
        buf[t] += a;
        __syncthreads();
    }
    int excl = part[blockIdx.x] + buf[t] - v;
    if (i < n) { rowptr[i] = excl; cursor[i] = excl; }
    if (i == n - 1) rowptr[n] = excl + v;
}

__global__ void scatter_csr(const int* __restrict__ src,
                            const int* __restrict__ dst,
                            int* __restrict__ cursor,
                            ushort_t* __restrict__ gsrc, int E) {
    int e = blockIdx.x * blockDim.x + threadIdx.x;
    if (e >= E) return;
    int pos = atomicAdd(&cursor[dst[e]], 1);
    gsrc[pos] = (ushort_t)src[e];
}

// ---------- fused kernels: 16-lane group per edge, 4 edges/wave ----------
// Branch-free, batched loads, scalar math (register-lean; R10's packed v2f
// raised VGPR 48->60 and cost occupancy -- reverted).

// layer 1: 4 heads x 32ch; head of lane = q>>2; reduce within 4 lanes.
__global__ __launch_bounds__(256) void node_fused1(
        const ushort_t* __restrict__ xlb,
        const float* __restrict__ xr,
        const float* __restrict__ att,
        const int* __restrict__ rowptr,
        const ushort_t* __restrict__ gsrc,
        const float* __restrict__ b,
        float* __restrict__ hout, int N) {
    const int wv = threadIdx.x >> 6;
    const int l  = threadIdx.x & 63;
    const int g  = l >> 4, q = l & 15;
    const int d  = blockIdx.x * 4 + wv;
    if (d >= N) return;
    const int beg = rowptr[d], end = rowptr[d + 1];
    const int cb = q * 8;
    const float4 xra = *(const float4*)&xr[(size_t)d * IN_C + cb];
    const float4 xrb = *(const float4*)&xr[(size_t)d * IN_C + cb + 4];
    float4 a6a = *(const float4*)&att[cb];
    float4 a6b = *(const float4*)&att[cb + 4];
    float4 a4a, a4b;
    a4a.x = 0.4f * a6a.x; a4a.y = 0.4f * a6a.y; a4a.z = 0.4f * a6a.z; a4a.w = 0.4f * a6a.w;
    a4b.x = 0.4f * a6b.x; a4b.y = 0.4f * a6b.y; a4b.z = 0.4f * a6b.z; a4b.w = 0.4f * a6b.w;
    a6a.x *= 0.6f; a6a.y *= 0.6f; a6a.z *= 0.6f; a6a.w *= 0.6f;
    a6b.x *= 0.6f; a6b.y *= 0.6f; a6b.z *= 0.6f; a6b.w *= 0.6f;
    float m = -1e30f, ls = 0.f;
    float4 acca = {0.f,0.f,0.f,0.f}, accb = {0.f,0.f,0.f,0.f};
    for (int c0 = beg; c0 < end; c0 += 16) {
        int sA[4];
#pragma unroll
        for (int u = 0; u < 4; ++u) {
            int j = c0 + 4 * u + g;
            sA[u] = (int)gsrc[min(j, end - 1)];
        }
        uint4 w[4];
#pragma unroll
        for (int u = 0; u < 4; ++u)
            w[u] = *(const uint4*)&xlb[(size_t)(sA[u] * IN_C) + cb];
        float f[4];
        float4 va[4], vb[4];
#pragma unroll
        for (int u = 0; u < 4; ++u) {
            float2 c01 = bf2f2(w[u].x), c23 = bf2f2(w[u].y);
            float2 c45 = bf2f2(w[u].z), c67 = bf2f2(w[u].w);
            va[u] = make_float4(c01.x, c01.y, c23.x, c23.y);
            vb[u] = make_float4(c45.x, c45.y, c67.x, c67.y);
            float p = 0.f, t;
            t = va[u].x + xra.x; p = fmaf(a6a.x, t, fmaf(a4a.x, fabsf(t), p));
            t = va[u].y + xra.y; p = fmaf(a6a.y, t, fmaf(a4a.y, fabsf(t), p));
            t = va[u].z + xra.z; p = fmaf(a6a.z, t, fmaf(a4a.z, fabsf(t), p));
            t = va[u].w + xra.w; p = fmaf(a6a.w, t, fmaf(a4a.w, fabsf(t), p));
            t = vb[u].x + xrb.x; p = fmaf(a6b.x, t, fmaf(a4b.x, fabsf(t), p));
            t = vb[u].y + xrb.y; p = fmaf(a6b.y, t, fmaf(a4b.y, fabsf(t), p));
            t = vb[u].z + xrb.z; p = fmaf(a6b.z, t, fmaf(a4b.z, fabsf(t), p));
            t = vb[u].w + xrb.w; p = fmaf(a6b.w, t, fmaf(a4b.w, fabsf(t), p));
            p += __shfl_xor(p, 1, 64);
            p += __shfl_xor(p, 2, 64);
            f[u] = (c0 + 4 * u + g < end) ? p : -1e30f;
        }
        float bm = fmaxf(fmaxf(f[0], f[1]), fmaxf(f[2], f[3]));
        float nm = fmaxf(m, bm);
        float fc = __expf(m - nm);
        ls *= fc;
        acca.x *= fc; acca.y *= fc; acca.z *= fc; acca.w *= fc;
        accb.x *= fc; accb.y *= fc; accb.z *= fc; accb.w *= fc;
#pragma unroll
        for (int u = 0; u < 4; ++u) {
            float wgt = __expf(f[u] - nm);
            ls += wgt;
            acca.x = fmaf(wgt, va[u].x, acca.x);
            acca.y = fmaf(wgt, va[u].y, acca.y);
            acca.z = fmaf(wgt, va[u].z, acca.z);
            acca.w = fmaf(wgt, va[u].w, acca.w);
            accb.x = fmaf(wgt, vb[u].x, accb.x);
            accb.y = fmaf(wgt, vb[u].y, accb.y);
            accb.z = fmaf(wgt, vb[u].z, accb.z);
            accb.w = fmaf(wgt, vb[u].w, accb.w);
        }
        m = nm;
    }
    // merge 4 groups (xor 16/32 partners share q -> same head)
#pragma unroll
    for (int o = 16; o <= 32; o <<= 1) {
        float mo = __shfl_xor(m, o, 64);
        float lo = __shfl_xor(ls, o, 64);
        float ax = __shfl_xor(acca.x, o, 64), ay = __shfl_xor(acca.y, o, 64);
        float az = __shfl_xor(acca.z, o, 64), aw = __shfl_xor(acca.w, o, 64);
        float bx = __shfl_xor(accb.x, o, 64), by = __shfl_xor(accb.y, o, 64);
        float bz = __shfl_xor(accb.z, o, 64), bw = __shfl_xor(accb.w, o, 64);
        float nm = fmaxf(m, mo);
        float fs = __expf(m - nm), fo = __expf(mo - nm);
        ls = ls * fs + lo * fo;
        acca.x = acca.x * fs + ax * fo; acca.y = acca.y * fs + ay * fo;
        acca.z = acca.z * fs + az * fo; acca.w = acca.w * fs + aw * fo;
        accb.x = accb.x * fs + bx * fo; accb.y = accb.y * fs + by * fo;
        accb.z = accb.z * fs + bz * fo; accb.w = accb.w * fs + bw * fo;
        m = nm;
    }
    if (g == 0) {
        float inv = (ls > 0.f) ? 1.f / ls : 0.f;
        const float4 b4a = *(const float4*)&b[cb];
        const float4 b4b = *(const float4*)&b[cb + 4];
        float4 o1, o2;
        o1.x = acca.x * inv + b4a.x; o1.y = acca.y * inv + b4a.y;
        o1.z = acca.z * inv + b4a.z; o1.w = acca.w * inv + b4a.w;
        o2.x = accb.x * inv + b4b.x; o2.y = accb.y * inv + b4b.y;
        o2.z = accb.z * inv + b4b.z; o2.w = accb.w * inv + b4b.w;
        o1.x = (o1.x > 0.f) ? o1.x : expm1f(o1.x);
        o1.y = (o1.y > 0.f) ? o1.y : expm1f(o1.y);
        o1.z = (o1.z > 0.f) ? o1.z : expm1f(o1.z);
        o1.w = (o1.w > 0.f) ? o1.w : expm1f(o1.w);
        o2.x = (o2.x > 0.f) ? o2.x : expm1f(o2.x);
        o2.y = (o2.y > 0.f) ? o2.y : expm1f(o2.y);
        o2.z = (o2.z > 0.f) ? o2.z : expm1f(o2.z);
        o2.w = (o2.w > 0.f) ? o2.w : expm1f(o2.w);
        *(float4*)&hout[(size_t)d * IN_C + cb]     = o1;
        *(float4*)&hout[(size_t)d * IN_C + cb + 4] = o2;
    }
}

// layer 2: single head x 128ch; reduce within all 16 lanes of the group.
__global__ __launch_bounds__(256) void node_fused2(
        const ushort_t* __restrict__ xlb,
        const float* __restrict__ xr,
        const float* __restrict__ att,
        const int* __restrict__ rowptr,
        const ushort_t* __restrict__ gsrc,
        const float* __restrict__ b,
        float* __restrict__ out, int N) {
    const int wv = threadIdx.x >> 6;
    const int l  = threadIdx.x & 63;
    const int g  = l >> 4, q = l & 15;
    const int d  = blockIdx.x * 4 + wv;
    if (d >= N) return;
    const int beg = rowptr[d], end = rowptr[d + 1];
    const int cb = q * 8;
    const float4 xra = *(const float4*)&xr[(size_t)d * OUT_C + cb];
    const float4 xrb = *(const float4*)&xr[(size_t)d * OUT_C + cb + 4];
    float4 a6a = *(const float4*)&att[cb];
    float4 a6b = *(const float4*)&att[cb + 4];
    float4 a4a, a4b;
    a4a.x = 0.4f * a6a.x; a4a.y = 0.4f * a6a.y; a4a.z = 0.4f * a6a.z; a4a.w = 0.4f * a6a.w;
    a4b.x = 0.4f * a6b.x; a4b.y = 0.4f * a6b.y; a4b.z = 0.4f * a6b.z; a4b.w = 0.4f * a6b.w;
    a6a.x *= 0.6f; a6a.y *= 0.6f; a6a.z *= 0.6f; a6a.w *= 0.6f;
    a6b.x *= 0.6f; a6b.y *= 0.6f; a6b.z *= 0.6f; a6b.w *= 0.6f;
    float m = -1e30f, ls = 0.f;
    float4 acca = {0.f,0.f,0.f,0.f}, accb = {0.f,0.f,0.f,0.f};
    for (int c0 = beg; c0 < end; c0 += 16) {
        int sA[4];
#pragma unroll
        for (int u = 0; u < 4; ++u) {
            int j = c0 + 4 * u + g;
            sA[u] = (int)gsrc[min(j, end - 1)];
        }
        uint4 w[4];
#pragma unroll
        for (int u = 0; u < 4; ++u)
            w[u] = *(const uint4*)&xlb[(size_t)(sA[u] * OUT_C) + cb];
        float f[4];
        float4 va[4], vb[4];
#pragma unroll
        for (int u = 0; u < 4; ++u) {
            float2 c01 = bf2f2(w[u].x), c23 = bf2f2(w[u].y);
            float2 c45 = bf2f2(w[u].z), c67 = bf2f2(w[u].w);
            va[u] = make_float4(c01.x, c01.y, c23.x, c23.y);
            vb[u] = make_float4(c45.x, c45.y, c67.x, c67.y);
            float p = 0.f, t;
            t = va[u].x + xra.x; p = fmaf(a6a.x, t, fmaf(a4a.x, fabsf(t), p));
            t = va[u].y + xra.y; p = fmaf(a6a.y, t, fmaf(a4a.y, fabsf(t), p));
            t = va[u].z + xra.z; p = fmaf(a6a.z, t, fmaf(a4a.z, fabsf(t), p));
            t = va[u].w + xra.w; p = fmaf(a6a.w, t, fmaf(a4a.w, fabsf(t), p));
            t = vb[u].x + xrb.x; p = fmaf(a6b.x, t, fmaf(a4b.x, fabsf(t), p));
            t = vb[u].y + xrb.y; p = fmaf(a6b.y, t, fmaf(a4b.y, fabsf(t), p));
            t = vb[u].z + xrb.z; p = fmaf(a6b.z, t, fmaf(a4b.z, fabsf(t), p));
            t = vb[u].w + xrb.w; p = fmaf(a6b.w, t, fmaf(a4b.w, fabsf(t), p));
            p += __shfl_xor(p, 1, 64);
            p += __shfl_xor(p, 2, 64);
            p += __shfl_xor(p, 4, 64);
            p += __shfl_xor(p, 8, 64);
            f[u] = (c0 + 4 * u + g < end) ? p : -1e30f;
        }
        float bm = fmaxf(fmaxf(f[0], f[1]), fmaxf(f[2], f[3]));
        float nm = fmaxf(m, bm);
        float fc = __expf(m - nm);
        ls *= fc;
        acca.x *= fc; acca.y *= fc; acca.z *= fc; acca.w *= fc;
        accb.x *= fc; accb.y *= fc; accb.z *= fc; accb.w *= fc;
#pragma unroll
        for (int u = 0; u < 4; ++u) {
            float wgt = __expf(f[u] - nm);
            ls += wgt;
            acca.x = fmaf(wgt, va[u].x, acca.x);
            acca.y = fmaf(wgt, va[u].y, acca.y);
            acca.z = fmaf(wgt, va[u].z, acca.z);
            acca.w = fmaf(wgt, va[u].w, acca.w);
            accb.x = fmaf(wgt, vb[u].x, accb.x);
            accb.y = fmaf(wgt, vb[u].y, accb.y);
            accb.z = fmaf(wgt, vb[u].z, accb.z);
            accb.w = fmaf(wgt, vb[u].w, accb.w);
        }
        m = nm;
    }
#pragma unroll
    for (int o = 16; o <= 32; o <<= 1) {
        float mo = __shfl_xor(m, o, 64);
        float lo = __shfl_xor(ls, o, 64);
        float ax = __shfl_xor(acca.x, o, 64), ay = __shfl_xor(acca.y, o, 64);
        float az = __shfl_xor(acca.z, o, 64), aw = __shfl_xor(acca.w, o, 64);
        float bx = __shfl_xor(accb.x, o, 64), by = __shfl_xor(accb.y, o, 64);
        float bz = __shfl_xor(accb.z, o, 64), bw = __shfl_xor(accb.w, o, 64);
        float nm = fmaxf(m, mo);
        float fs = __expf(m - nm), fo = __expf(mo - nm);
        ls = ls * fs + lo * fo;
        acca.x = acca.x * fs + ax * fo; acca.y = acca.y * fs + ay * fo;
        acca.z = acca.z * fs + az * fo; acca.w = acca.w * fs + aw * fo;
        accb.x = accb.x * fs + bx * fo; accb.y = accb.y * fs + by * fo;
        accb.z = accb.z * fs + bz * fo; accb.w = accb.w * fs + bw * fo;
        m = nm;
    }
    if (g == 0) {
        float inv = (ls > 0.f) ? 1.f / ls : 0.f;
        const float4 b4a = *(const float4*)&b[cb];
        const float4 b4b = *(const float4*)&b[cb + 4];
        float4 o1, o2;
        o1.x = acca.x * inv + b4a.x; o1.y = acca.y * inv + b4a.y;
        o1.z = acca.z * inv + b4a.z; o1.w = acca.w * inv + b4a.w;
        o2.x = accb.x * inv + b4b.x; o2.y = accb.y * inv + b4b.y;
        o2.z = accb.z * inv + b4b.z; o2.w = accb.w * inv + b4b.w;
        *(float4*)&out[(size_t)d * OUT_C + cb]     = o1;
        *(float4*)&out[(size_t)d * OUT_C + cb + 4] = o2;
    }
}

extern "C" void kernel_launch(void* const* d_in, const int* in_sizes, int n_in,
                              void* d_out, int out_size, void* d_ws, size_t ws_size,
                              hipStream_t stream) {
    const float* x    = (const float*)d_in[0];
    const int*   ei   = (const int*)d_in[1];
    const float* W1l  = (const float*)d_in[2];
    const float* W1r  = (const float*)d_in[3];
    const float* att1 = (const float*)d_in[4];
    const float* b1   = (const float*)d_in[5];
    const float* W2l  = (const float*)d_in[6];
    const float* W2r  = (const float*)d_in[7];
    const float* att2 = (const float*)d_in[8];
    const float* b2   = (const float*)d_in[9];

    const int N = in_sizes[0] / IN_C;
    const int E = in_sizes[1] / 2;
    const int* src = ei;
    const int* dst = ei + E;

    // workspace layout
    float* ws = (float*)d_ws;
    size_t o = 0;
    ushort_t* xlb = (ushort_t*)(ws + o); o += (size_t)N * IN_C / 2;  // bf16 x@Wl / h@W2l
    float* xr   = ws + o; o += (size_t)N * IN_C;   // x@Wr (layer1) / h@W2r (layer2)
    float* hbuf = ws + o; o += (size_t)N * IN_C;   // layer1 output h (post ELU, f32)
    int* iws    = (int*)(ws + o);
    int* rowptr = iws;                    // N+1
    int* cnt    = iws + (N + 1);          // N
    int* cursor = iws + (N + 1) + N;      // N   (seeded by scan_final)
    int* part   = iws + (N + 1) + 2 * N;  // <=1024 block partials
    ushort_t* gsrc = (ushort_t*)(iws + (N + 1) + 2 * N + 1024);  // E (CSR src ids)

    hipMemsetAsync(cnt, 0, (size_t)N * 4, stream);

    const int B = 256;
    const int nb = (N + 255) / 256;   // scan blocks (196 <= 1024)
    // ---- CSR by dst (shared by both layers) ----
    hist_kernel<<<(E + B - 1) / B, B, 0, stream>>>(dst, cnt, E);
    scan_block_sums<<<nb, 256, 0, stream>>>(cnt, part, N);
    scan_part_excl<<<1, 1024, 0, stream>>>(part, nb);
    scan_final<<<nb, 256, 0, stream>>>(cnt, part, rowptr, cursor, N);
    scatter_csr<<<(E + B - 1) / B, B, 0, stream>>>(src, dst, cursor, gsrc, E);

    // ---- layer 1 ----
    transform_mfma<<<512, 256, 0, stream>>>(x, W1l, W1r, xlb, xr, N);
    node_fused1<<<(N + 3) / 4, 256, 0, stream>>>(xlb, xr, att1, rowptr, gsrc, b1, hbuf, N);

    // ---- layer 2 ----
    transform_mfma<<<512, 256, 0, stream>>>(hbuf, W2l, W2r, xlb, xr, N);
    node_fused2<<<(N + 3) / 4, 256, 0, stream>>>(xlb, xr, att2, rowptr, gsrc, b2, (float*)d_out, N);
}